// Round 2
// baseline (553.215 us; speedup 1.0000x reference)
//
#include <hip/hip_runtime.h>
#include <hip/hip_bf16.h>

#define B_ 8
#define C_ 1536
#define T_ 4096
#define A_ 128
#define K3_ 4608        // 3*C columns of W1
#define M32_ 128        // T / 32 chunks
#define KP_ 200         // fallback k2 tile row stride (f16 elems)
#define NKB_ 144        // K3/32 k-blocks
#define N16_ 256        // T/16 t-groups

typedef _Float16 h8  __attribute__((ext_vector_type(8)));
typedef _Float16 h2v __attribute__((ext_vector_type(2)));
typedef float    f4  __attribute__((ext_vector_type(4)));

// ---------------- kernel 0: W1 fp32 -> f16, MFMA A-fragment order -----------
// W1f[((kb*8 + t8)*64 + lane)*8 + j] = W1[a=t8*16+(lane&15)][k=kb*32+(lane>>4)*8+j]
__global__ void k0_pack(const float* __restrict__ W1, _Float16* __restrict__ W1f) {
    int i = blockIdx.x * 256 + threadIdx.x;
    if (i >= A_ * K3_) return;
    int a = i / K3_, k = i - a * K3_;
    int t8 = a >> 4, r15 = a & 15;
    int kb = k >> 5, q = (k >> 3) & 3, j = k & 7;
    int lane = q * 16 + r15;
    W1f[(size_t)((kb * 8 + t8) * 64 + lane) * 8 + j] = (_Float16)W1[i];
}

// ======================= NEW PATH (needs ~304 MB ws) ========================
// ---------------- kernel 1n: full stats -> packed attn_in P (f16) -----------
// Block: (b, 8-channel group). 8 waves, wave w owns channel c0+w.
// Per 256-t group g: coalesced float4 load, 64-lane scan -> mean/std per t,
// f16 triple staged in LDS (XOR-swizzled 16B units), then transposed writes:
// P fragment block (b,n16,kb): 64 lanes x 8 k-consecutive f16 (1 KB).
// This block supplies q-slot q=(c0>>3)&3 of kb = p*48 + c0/32, p=0..2.
__global__ __launch_bounds__(512) void k1_stats(
    const float* __restrict__ x, const int* __restrict__ lens,
    _Float16* __restrict__ P)
{
    __shared__ _Float16 lds[768 * 8];   // 768 16-B units = 12 KB
    const int blk = blockIdx.x;
    const int b   = blk / 192;
    const int c8  = blk - b * 192;
    const int c0  = c8 * 8;
    const int tid = threadIdx.x, lane = tid & 63, w = tid >> 6;
    const int len = lens[b];
    const float* xr = x + ((size_t)b * C_ + c0 + w) * T_;
    _Float16* Pb = P + (size_t)b * N16_ * NKB_ * 64 * 8;
    const int q = (c0 >> 3) & 3;
    const int kb_base = c0 >> 5;
    const int r16 = tid & 15, grp = tid >> 4;   // writer mapping

    float base1 = 0.f, base2 = 0.f;
    for (int g = 0; g < 16; ++g) {
        const int t0g = g * 256;
        const int tb  = t0g + lane * 4;
        float4 v = *(const float4*)(xr + tb);
        float vs[4] = {v.x, v.y, v.z, v.w};
        float p1[4], p2[4];
        float s1 = 0.f, s2 = 0.f;
#pragma unroll
        for (int j = 0; j < 4; ++j) {
            float xv = vs[j];
            float mm = (tb + j < len) ? xv : 0.f;
            s1 += mm; s2 += mm * xv;
            p1[j] = s1; p2[j] = s2;
        }
        float V1 = s1, V2 = s2;
#pragma unroll
        for (int d = 1; d < 64; d <<= 1) {
            float o1 = __shfl_up(V1, d, 64);
            float o2 = __shfl_up(V2, d, 64);
            if (lane >= d) { V1 += o1; V2 += o2; }
        }
        const float e1 = base1 + (V1 - s1);
        const float e2 = base2 + (V2 - s2);
        base1 += __shfl(V1, 63, 64);
        base2 += __shfl(V2, 63, 64);
#pragma unroll
        for (int j = 0; j < 4; ++j) {
            const int t  = tb + j;
            const int tl = lane * 4 + j;          // 0..255
            float S1 = e1 + p1[j], S2 = e2 + p2[j];
            float rn = __builtin_amdgcn_rcpf((float)min(t + 1, len));
            float mn = S1 * rn;
            float var = S2 * rn - mn * mn;
            float sd = sqrtf(fmaxf(var, 1e-12f));
            int u0 = tl * 3;
            int a0 = (u0 + 0) ^ (((u0 + 0) >> 3) & 7);
            int a1 = (u0 + 1) ^ (((u0 + 1) >> 3) & 7);
            int a2 = (u0 + 2) ^ (((u0 + 2) >> 3) & 7);
            lds[a0 * 8 + w] = (_Float16)vs[j];
            lds[a1 * 8 + w] = (_Float16)mn;
            lds[a2 * 8 + w] = (_Float16)sd;
        }
        __syncthreads();
        // transpose-out: 48 (n16l,p) groups x 16 lanes, 16 B each
#pragma unroll
        for (int it = 0; it < 2; ++it) {
            int idx = it * 32 + grp;
            if (idx < 48) {
                int n16l = idx / 3, p = idx - n16l * 3;
                int tl = n16l * 16 + r16;
                int u = tl * 3 + p;
                int a = u ^ ((u >> 3) & 7);
                h8 pay = *(const h8*)&lds[a * 8];
                int n16 = g * 16 + n16l;
                int kbp = p * 48 + kb_base;
                *(h8*)(Pb + (((size_t)(n16 * NKB_ + kbp)) * 64 + q * 16 + r16) * 8) = pay;
            }
        }
        __syncthreads();
    }
}

// ---------------- kernel 2n: pure GEMM from packed P, no LDS, no barriers ---
// grid 512 = (b, 64-t chunk). 4 waves: mtg = a-half(64), ntg = t-half(32).
// Per kb: 2 bf (coalesced 1KB, read-once HBM) + 4 af (L1/L2 W1f) + 8 MFMA.
__global__ __launch_bounds__(256) void k2_pure(
    const _Float16* __restrict__ P, const _Float16* __restrict__ W1f,
    const float* __restrict__ b1, const float* __restrict__ W2,
    float* __restrict__ logits)
{
    __shared__ float s_w2[A_], s_b1[A_];
    __shared__ float lpart[2][64];
    const int tid = threadIdx.x, lane = tid & 63, w = tid >> 6;
    const int mtg = w & 1, ntg = w >> 1;
    if (tid < A_) { s_w2[tid] = W2[tid]; s_b1[tid] = b1[tid]; }
    const int bid = blockIdx.x;
    const int b   = bid >> 6, t64 = bid & 63;
    const int n16_0 = t64 * 4 + ntg * 2;
    const h8* W1f8 = (const h8*)W1f;
    const h8* p0 = (const h8*)P + (size_t)b * N16_ * NKB_ * 64
                 + (size_t)(n16_0 + 0) * NKB_ * 64 + lane;
    const h8* p1 = p0 + (size_t)NKB_ * 64;
    const h8* wf = W1f8 + mtg * 4 * 64 + lane;

    f4 acc[2][4] = {};
#pragma unroll 3
    for (int kb = 0; kb < NKB_; ++kb) {
        h8 bf0 = p0[kb * 64];
        h8 bf1 = p1[kb * 64];
#pragma unroll
        for (int ii = 0; ii < 4; ++ii) {
            h8 af = wf[(kb * 8 + ii) * 64];
            acc[0][ii] = __builtin_amdgcn_mfma_f32_16x16x32_f16(af, bf0, acc[0][ii], 0, 0, 0);
            acc[1][ii] = __builtin_amdgcn_mfma_f32_16x16x32_f16(af, bf1, acc[1][ii], 0, 0, 0);
        }
    }
    __syncthreads();
    const int q = lane >> 4, ln15 = lane & 15;
    float pr[2] = {0.f, 0.f};
#pragma unroll
    for (int nn = 0; nn < 2; ++nn) {
#pragma unroll
        for (int ii = 0; ii < 4; ++ii) {
#pragma unroll
            for (int rg = 0; rg < 4; ++rg) {
                int a = (mtg * 4 + ii) * 16 + q * 4 + rg;
                float h = acc[nn][ii][rg] + s_b1[a];
                pr[nn] += tanhf(h) * s_w2[a];
            }
        }
        pr[nn] += __shfl_xor(pr[nn], 16, 64);
        pr[nn] += __shfl_xor(pr[nn], 32, 64);
        if (q == 0) lpart[mtg][ntg * 32 + nn * 16 + ln15] = pr[nn];
    }
    __syncthreads();
    if (tid < 64) {
        logits[(size_t)b * T_ + t64 * 64 + tid] = lpart[0][tid] + lpart[1][tid];
    }
}

// ======================= FALLBACK PATH (round-1, small ws) ==================
__global__ __launch_bounds__(256) void k1_carry(
    const float* __restrict__ x, const int* __restrict__ lens,
    float2* __restrict__ carry)
{
    const int rowid = blockIdx.x * 4 + (threadIdx.x >> 6);
    const int lane  = threadIdx.x & 63;
    const int b     = rowid / C_;
    const int len   = lens[b];
    const float* xr = x + (size_t)rowid * T_;
    float2* cp = carry + (size_t)rowid * M32_;
    const int grp = lane >> 3;
    float base1 = 0.f, base2 = 0.f;
#pragma unroll
    for (int g = 0; g < 16; ++g) {
        const int t0g = g * 256;
        if (t0g >= len) {
            if ((lane & 7) == 0) cp[g * 8 + grp] = make_float2(base1, base2);
            continue;
        }
        float4 v = *(const float4*)(xr + t0g + lane * 4);
        float s1, s2;
        if (t0g + 256 <= len) {
            s1 = v.x + v.y + v.z + v.w;
            s2 = v.x * v.x + v.y * v.y + v.z * v.z + v.w * v.w;
        } else {
            const int tb = t0g + lane * 4;
            float vs[4] = {v.x, v.y, v.z, v.w};
            s1 = 0.f; s2 = 0.f;
#pragma unroll
            for (int j = 0; j < 4; ++j) {
                float m = (tb + j < len) ? vs[j] : 0.f;
                s1 += m; s2 += m * vs[j];
            }
        }
        float g1 = s1, g2 = s2;
        g1 += __shfl_xor(g1, 1, 64); g2 += __shfl_xor(g2, 1, 64);
        g1 += __shfl_xor(g1, 2, 64); g2 += __shfl_xor(g2, 2, 64);
        g1 += __shfl_xor(g1, 4, 64); g2 += __shfl_xor(g2, 4, 64);
        float V1 = g1, V2 = g2;
#pragma unroll
        for (int d = 8; d < 64; d <<= 1) {
            float o1 = __shfl_up(V1, d, 64);
            float o2 = __shfl_up(V2, d, 64);
            if (lane >= d) { V1 += o1; V2 += o2; }
        }
        const float e1 = V1 - g1, e2 = V2 - g2;
        if ((lane & 7) == 0) cp[g * 8 + grp] = make_float2(base1 + e1, base2 + e2);
        base1 += __shfl(V1, 63, 64);
        base2 += __shfl(V2, 63, 64);
    }
}

__global__ __launch_bounds__(256) void k2_gemm(
    const float* __restrict__ x, const int* __restrict__ lens,
    const float2* __restrict__ carry, const _Float16* __restrict__ W1f,
    const float* __restrict__ b1, const float* __restrict__ W2,
    float* __restrict__ logits)
{
    __shared__ _Float16 tile[32][KP_];
    __shared__ float s_w2[A_], s_b1[A_];
    __shared__ float lpart[2][32];
    const int tid = threadIdx.x;
    const int i    = blockIdx.x;
    const int mlow = i >> 7;
    const int b    = (i >> 4) & 7;
    const int m    = ((i & 15) << 3) | mlow;
    const int t0   = m << 5;
    const int len  = lens[b];
    if (tid < A_) { s_w2[tid] = W2[tid]; s_b1[tid] = b1[tid]; }
    const int cp  = tid >> 3;
    const int sgm = tid & 7;
    const int tb  = t0 + sgm * 4;
    const int lane = tid & 63;
    const int w    = tid >> 6;
    const int mtg  = w & 1;
    const int ntg  = w >> 1;
    const int ln15 = lane & 15, q = lane >> 4;
    const h8* W1f8 = (const h8*)W1f;
    f4 acc[4] = {};
    for (int c0 = 0; c0 < C_; c0 += 64) {
        const size_t rowA = (size_t)b * C_ + c0 + cp * 2;
        const float* xpA = x + rowA * T_ + tb;
        float4 va = *(const float4*)xpA;
        float4 vb = *(const float4*)(xpA + T_);
        float xa[4] = {va.x, va.y, va.z, va.w};
        float xb[4] = {vb.x, vb.y, vb.z, vb.w};
        float pA1[4], pA2[4], pB1[4], pB2[4];
        float a1 = 0.f, a2 = 0.f, c1 = 0.f, c2 = 0.f;
#pragma unroll
        for (int j = 0; j < 4; ++j) {
            bool in = (tb + j) < len;
            float ma = in ? xa[j] : 0.f;
            float mb = in ? xb[j] : 0.f;
            a1 += ma; a2 += ma * xa[j]; pA1[j] = a1; pA2[j] = a2;
            c1 += mb; c2 += mb * xb[j]; pB1[j] = c1; pB2[j] = c2;
        }
        float t1 = a1, t2 = a2, t3 = c1, t4 = c2;
#pragma unroll
        for (int d = 1; d < 8; d <<= 1) {
            float o1 = __shfl_up(t1, d, 8);
            float o2 = __shfl_up(t2, d, 8);
            float o3 = __shfl_up(t3, d, 8);
            float o4 = __shfl_up(t4, d, 8);
            if (sgm >= d) { t1 += o1; t2 += o2; t3 += o3; t4 += o4; }
        }
        const float eA1 = t1 - a1, eA2 = t2 - a2;
        const float eB1 = t3 - c1, eB2 = t4 - c2;
        const float2 crA = carry[rowA * M32_ + m];
        const float2 crB = carry[(rowA + 1) * M32_ + m];
        const int cb = cp >> 2;
        const int co = (cp & 3) * 2;
#pragma unroll
        for (int j = 0; j < 4; ++j) {
            const int t  = tb + j;
            const int tl = sgm * 4 + j;
            float fn = (float)min(t + 1, len);
            float rn = __builtin_amdgcn_rcpf(fn);
            float S1a = crA.x + eA1 + pA1[j];
            float S2a = crA.y + eA2 + pA2[j];
            float mA = S1a * rn;
            float vA = S2a * rn - mA * mA;
            float dA = sqrtf(fmaxf(vA, 1e-12f));
            float S1b = crB.x + eB1 + pB1[j];
            float S2b = crB.y + eB2 + pB2[j];
            float mB = S1b * rn;
            float vB = S2b * rn - mB * mB;
            float dB = sqrtf(fmaxf(vB, 1e-12f));
            const int s  = (tl >> 3) & 3;
            const int xo = ((cb ^ s) << 3) + co;
            h2v px = {(_Float16)xa[j], (_Float16)xb[j]};
            h2v pm = {(_Float16)mA, (_Float16)mB};
            h2v pd = {(_Float16)dA, (_Float16)dB};
            *(h2v*)&tile[tl][xo]       = px;
            *(h2v*)&tile[tl][64 + xo]  = pm;
            *(h2v*)&tile[tl][128 + xo] = pd;
        }
        __syncthreads();
        const int tl = ntg * 16 + ln15;
        const int s  = (tl >> 3) & 3;
        const int kb0 = c0 >> 5;
#pragma unroll
        for (int p = 0; p < 3; ++p) {
#pragma unroll
            for (int kk = 0; kk < 2; ++kk) {
                const int bb = (kk * 4 + q) ^ s;
                h8 bf = *(const h8*)&tile[tl][p * 64 + bb * 8];
                const int kbp = p * 48 + kb0 + kk;
#pragma unroll
                for (int ii = 0; ii < 4; ++ii) {
                    h8 af = W1f8[(kbp * 8 + mtg * 4 + ii) * 64 + lane];
                    acc[ii] = __builtin_amdgcn_mfma_f32_16x16x32_f16(af, bf, acc[ii], 0, 0, 0);
                }
            }
        }
        __syncthreads();
    }
    float pr = 0.f;
#pragma unroll
    for (int ii = 0; ii < 4; ++ii) {
#pragma unroll
        for (int rg = 0; rg < 4; ++rg) {
            int a = (mtg * 4 + ii) * 16 + q * 4 + rg;
            float h = acc[ii][rg] + s_b1[a];
            pr += tanhf(h) * s_w2[a];
        }
    }
    pr += __shfl_xor(pr, 16, 64);
    pr += __shfl_xor(pr, 32, 64);
    if (q == 0) lpart[mtg][ntg * 16 + ln15] = pr;
    __syncthreads();
    if (tid < 32) logits[(size_t)b * T_ + t0 + tid] = lpart[0][tid] + lpart[1][tid];
}

// ---------------- kernel 3: softmax prep (e, cumsum Z) per b ----------------
// 1024 threads (16 waves) per b. Max-subtraction dropped: e,Z only ever used
// as ratios in k4, so the exp(max) scale cancels; |logits| <= ~10 (tanh*W2).
__global__ __launch_bounds__(1024) void k3_softmax(
    const float* __restrict__ logits, float* __restrict__ earr,
    float* __restrict__ zarr)
{
    __shared__ float wsum[16];
    const int b = blockIdx.x, tid = threadIdx.x, lane = tid & 63, w = tid >> 6;
    float4 v = *(const float4*)(logits + (size_t)b * T_ + tid * 4);
    float e0 = expf(v.x), e1 = expf(v.y), e2 = expf(v.z), e3 = expf(v.w);
    float s = (e0 + e1) + (e2 + e3);
    float V = s;
#pragma unroll
    for (int d = 1; d < 64; d <<= 1) {
        float o = __shfl_up(V, d, 64);
        if (lane >= d) V += o;
    }
    if (lane == 63) wsum[w] = V;
    __syncthreads();
    float wb = 0.f;
#pragma unroll
    for (int i = 0; i < 16; ++i) wb += (i < w) ? wsum[i] : 0.f;
    float run = wb + (V - s);
    float4 ev, zv;
    ev.x = e0; run += e0; zv.x = run;
    ev.y = e1; run += e1; zv.y = run;
    ev.z = e2; run += e2; zv.z = run;
    ev.w = e3; run += e3; zv.w = run;
    *(float4*)(earr + (size_t)b * T_ + tid * 4) = ev;
    *(float4*)(zarr + (size_t)b * T_ + tid * 4) = zv;
}

// ---------------- kernel 4: weighted running mean/std + final reduce --------
__global__ __launch_bounds__(256) void k4_wstats(
    const float* __restrict__ x, const float* __restrict__ earr,
    const float* __restrict__ zarr, float* __restrict__ out)
{
    const int rowid = blockIdx.x * 4 + (threadIdx.x >> 6);
    const int lane  = threadIdx.x & 63;
    const int b = rowid / C_;
    const int c = rowid - b * C_;
    const float* xr = x + (size_t)rowid * T_;
    const float* er = earr + (size_t)b * T_;
    const float* zr = zarr + (size_t)b * T_;
    float am = 0.f, asd = 0.f;
    float baseS = 0.f, baseD = 0.f;
#pragma unroll
    for (int g = 0; g < 16; ++g) {
        const int off = g * 256 + lane * 4;
        float4 xv = *(const float4*)(xr + off);
        float4 ev = *(const float4*)(er + off);
        float4 zv = *(const float4*)(zr + off);
        float s0 = ev.x * xv.x;
        float s1 = s0 + ev.y * xv.y;
        float s2 = s1 + ev.z * xv.z;
        float s3 = s2 + ev.w * xv.w;
        float V = s3;
#pragma unroll
        for (int d = 1; d < 64; d <<= 1) {
            float o = __shfl_up(V, d, 64);
            if (lane >= d) V += o;
        }
        const float Sx = baseS + (V - s3);
        baseS += __shfl(V, 63, 64);
        const float rz0 = __builtin_amdgcn_rcpf(zv.x);
        const float rz1 = __builtin_amdgcn_rcpf(zv.y);
        const float rz2 = __builtin_amdgcn_rcpf(zv.z);
        const float rz3 = __builtin_amdgcn_rcpf(zv.w);
        const float wm0 = (Sx + s0) * rz0;
        const float wm1 = (Sx + s1) * rz1;
        const float wm2 = (Sx + s2) * rz2;
        const float wm3 = (Sx + s3) * rz3;
        am += (wm0 + wm1) + (wm2 + wm3);
        const float d0 = xv.x - wm0;
        const float d1 = xv.y - wm1;
        const float d2 = xv.z - wm2;
        const float d3 = xv.w - wm3;
        float q0 = ev.x * d0 * d0;
        float q1 = q0 + ev.y * d1 * d1;
        float q2 = q1 + ev.z * d2 * d2;
        float q3 = q2 + ev.w * d3 * d3;
        float W = q3;
#pragma unroll
        for (int d = 1; d < 64; d <<= 1) {
            float o = __shfl_up(W, d, 64);
            if (lane >= d) W += o;
        }
        const float Dx = baseD + (W - q3);
        baseD += __shfl(W, 63, 64);
        const float v0 = (Dx + q0) * rz0;
        const float v1 = (Dx + q1) * rz1;
        const float v2 = (Dx + q2) * rz2;
        const float v3 = (Dx + q3) * rz3;
        asd += (sqrtf(fmaxf(v0, 1e-12f)) + sqrtf(fmaxf(v1, 1e-12f)))
             + (sqrtf(fmaxf(v2, 1e-12f)) + sqrtf(fmaxf(v3, 1e-12f)));
    }
#pragma unroll
    for (int d = 1; d < 64; d <<= 1) {
        am  += __shfl_xor(am, d, 64);
        asd += __shfl_xor(asd, d, 64);
    }
    if (lane == 0) {
        out[(size_t)b * (2 * C_) + c]      = am  * (1.f / 4096.f);
        out[(size_t)b * (2 * C_) + C_ + c] = asd * (1.f / 4096.f);
    }
}

extern "C" void kernel_launch(void* const* d_in, const int* in_sizes, int n_in,
                              void* d_out, int out_size, void* d_ws, size_t ws_size,
                              hipStream_t stream) {
    const float* x    = (const float*)d_in[0];
    const int*   lens = (const int*)d_in[1];
    const float* W1   = (const float*)d_in[2];
    const float* b1   = (const float*)d_in[3];
    const float* W2   = (const float*)d_in[4];
    float* out = (float*)d_out;
    char* ws = (char*)d_ws;

    const size_t P_BYTES   = (size_t)B_ * N16_ * NKB_ * 64 * 8 * 2;  // 301,989,888
    const size_t W1F_BYTES = (size_t)A_ * K3_ * 2;                   //   1,179,648
    const size_t LG_BYTES  = (size_t)B_ * T_ * 4;                    //     131,072
    const size_t NEED      = P_BYTES + W1F_BYTES + 3 * LG_BYTES;

    if (ws_size >= NEED) {
        _Float16* P      = (_Float16*)ws;
        _Float16* W1f    = (_Float16*)(ws + P_BYTES);
        float*    logits = (float*)(ws + P_BYTES + W1F_BYTES);
        float*    earr   = (float*)(ws + P_BYTES + W1F_BYTES + LG_BYTES);
        float*    zarr   = (float*)(ws + P_BYTES + W1F_BYTES + 2 * LG_BYTES);
        k0_pack   <<<(A_ * K3_ + 255) / 256, 256, 0, stream>>>(W1, W1f);
        k1_stats  <<<B_ * (C_ / 8), 512, 0, stream>>>(x, lens, P);
        k2_pure   <<<B_ * 64, 256, 0, stream>>>(P, W1f, b1, W2, logits);
        k3_softmax<<<B_, 1024, 0, stream>>>(logits, earr, zarr);
        k4_wstats <<<(B_ * C_) / 4, 256, 0, stream>>>(x, earr, zarr, out);
    } else {
        // fallback: round-1 pipeline (14.16 MB ws)
        float2*    carry  = (float2*)ws;                     // 12,582,912
        _Float16*  W1f    = (_Float16*)(ws + 12582912);      //  1,179,648
        float*     logits = (float*)(ws + 13762560);
        float*     earr   = (float*)(ws + 13893632);
        float*     zarr   = (float*)(ws + 14024704);
        k0_pack   <<<(A_ * K3_ + 255) / 256, 256, 0, stream>>>(W1, W1f);
        k1_carry  <<<(B_ * C_) / 4, 256, 0, stream>>>(x, lens, carry);
        k2_gemm   <<<B_ * M32_, 256, 0, stream>>>(x, lens, carry, W1f, b1, W2, logits);
        k3_softmax<<<B_, 1024, 0, stream>>>(logits, earr, zarr);
        k4_wstats <<<(B_ * C_) / 4, 256, 0, stream>>>(x, earr, zarr, out);
    }
}

// Round 3
// 470.898 us; speedup vs baseline: 1.1748x; 1.1748x over previous
//
#include <hip/hip_runtime.h>
#include <hip/hip_bf16.h>

#define B_ 8
#define C_ 1536
#define T_ 4096
#define A_ 128
#define K3_ 4608        // 3*C columns of W1
#define M32_ 128        // T / 32 chunks
#define SCW_ 104        // k2f scratch row stride (f16 elems), 2-way banks, 16B-aligned

typedef _Float16 h8  __attribute__((ext_vector_type(8)));
typedef float    f4  __attribute__((ext_vector_type(4)));

// ---------------- kernel 0: W1 fp32 -> f16, MFMA A-fragment order -----------
// W1f[((kb*8 + t8)*64 + lane)*8 + j] = W1[a=t8*16+(lane&15)][k=kb*32+(lane>>4)*8+j]
__global__ void k0_pack(const float* __restrict__ W1, _Float16* __restrict__ W1f) {
    int i = blockIdx.x * 256 + threadIdx.x;
    if (i >= A_ * K3_) return;
    int a = i / K3_, k = i - a * K3_;
    int t8 = a >> 4, r15 = a & 15;
    int kb = k >> 5, q = (k >> 3) & 3, j = k & 7;
    int lane = q * 16 + r15;
    W1f[(size_t)((kb * 8 + t8) * 64 + lane) * 8 + j] = (_Float16)W1[i];
}

// ---------------- kernel 1: per-(b,c) 32-t-chunk carries (row-major) --------
__global__ __launch_bounds__(256) void k1_carry(
    const float* __restrict__ x, const int* __restrict__ lens,
    float2* __restrict__ carry)
{
    const int rowid = blockIdx.x * 4 + (threadIdx.x >> 6);
    const int lane  = threadIdx.x & 63;
    const int b     = rowid / C_;
    const int len   = lens[b];
    const float* xr = x + (size_t)rowid * T_;
    float2* cp = carry + (size_t)rowid * M32_;
    const int grp = lane >> 3;
    float base1 = 0.f, base2 = 0.f;
#pragma unroll
    for (int g = 0; g < 16; ++g) {
        const int t0g = g * 256;
        if (t0g >= len) {
            if ((lane & 7) == 0) cp[g * 8 + grp] = make_float2(base1, base2);
            continue;
        }
        float4 v = *(const float4*)(xr + t0g + lane * 4);
        float s1, s2;
        if (t0g + 256 <= len) {
            s1 = v.x + v.y + v.z + v.w;
            s2 = v.x * v.x + v.y * v.y + v.z * v.z + v.w * v.w;
        } else {
            const int tb = t0g + lane * 4;
            float vs[4] = {v.x, v.y, v.z, v.w};
            s1 = 0.f; s2 = 0.f;
#pragma unroll
            for (int j = 0; j < 4; ++j) {
                float m = (tb + j < len) ? vs[j] : 0.f;
                s1 += m; s2 += m * vs[j];
            }
        }
        float g1 = s1, g2 = s2;
        g1 += __shfl_xor(g1, 1, 64); g2 += __shfl_xor(g2, 1, 64);
        g1 += __shfl_xor(g1, 2, 64); g2 += __shfl_xor(g2, 2, 64);
        g1 += __shfl_xor(g1, 4, 64); g2 += __shfl_xor(g2, 4, 64);
        float V1 = g1, V2 = g2;
#pragma unroll
        for (int d = 8; d < 64; d <<= 1) {
            float o1 = __shfl_up(V1, d, 64);
            float o2 = __shfl_up(V2, d, 64);
            if (lane >= d) { V1 += o1; V2 += o2; }
        }
        const float e1 = V1 - g1, e2 = V2 - g2;
        if ((lane & 7) == 0) cp[g * 8 + grp] = make_float2(base1 + e1, base2 + e2);
        base1 += __shfl(V1, 63, 64);
        base2 += __shfl(V2, 63, 64);
    }
}

// ---------------- kernel 1b: carry transpose -> carryT[b][m][c] -------------
// so k2f's per-step carry read (32 consecutive channels) is contiguous.
__global__ __launch_bounds__(256) void k1b_T(
    const float2* __restrict__ carry, float2* __restrict__ carryT)
{
    __shared__ float2 t[64][65];
    const int bid = blockIdx.x;        // 8 * 24 * 2 = 384
    const int b = bid / 48;
    const int r = bid - b * 48;
    const int ct = r >> 1, mt = r & 1;
    const int c0 = ct * 64, m0 = mt * 64;
    const int tx = threadIdx.x & 63, ty = threadIdx.x >> 6;
#pragma unroll
    for (int i = 0; i < 16; ++i) {
        int cl = i * 4 + ty;
        t[cl][tx] = carry[((size_t)(b * C_ + c0 + cl)) * M32_ + m0 + tx];
    }
    __syncthreads();
#pragma unroll
    for (int i = 0; i < 16; ++i) {
        int ml = i * 4 + ty;
        carryT[((size_t)b * M32_ + m0 + ml) * C_ + c0 + tx] = t[tx][ml];
    }
}

// ---------------- kernel 2f: fused stats+GEMM, wave-autonomous --------------
// grid 512 = (b, 64-t pair). 4 waves = 2 K-halves x 2 32-t chunks.
// Wave loop over 24 c-steps of 32 channels: lane = (channel kc, t-half th).
// Stats: in-register 16-prefix + shfl_xor(1) + carryT. LDS scratch is
// wave-private (32 x 104 f16) -> NO barriers in main loop. B-frags via
// ds_read_b128. af streamed from L2-resident W1f. 2 barriers total for the
// split-K reduce + tanh/W2 epilogue.
__global__ __launch_bounds__(256, 2) void k2f(
    const float* __restrict__ x, const int* __restrict__ lens,
    const float2* __restrict__ carryT, const _Float16* __restrict__ W1f,
    const float* __restrict__ b1, const float* __restrict__ W2,
    float* __restrict__ logits)
{
    __shared__ __align__(16) char smem[32768];   // scratch (26.6KB) / reduce (32KB)
    __shared__ float s_b1[A_], s_w2[A_];

    const int tid = threadIdx.x, lane = tid & 63, w = tid >> 6;
    const int s   = w & 1;               // K-half: channels [s*768, s*768+768)
    const int tch = w >> 1;              // t-chunk within block
    const int bid = blockIdx.x;
    const int b   = bid >> 6;
    const int m   = ((bid & 63) << 1) + tch;   // 0..127
    const int t0  = m << 5;
    const int len = lens[b];
    if (tid < A_) { s_b1[tid] = b1[tid]; s_w2[tid] = W2[tid]; }

    const int kc = lane >> 1;            // channel within 32-group
    const int th = lane & 1;             // t-half (16 t)
    const int c_base = s * 768;
    _Float16* sc = (_Float16*)smem + w * (32 * SCW_);
    const h8* W1f8 = (const h8*)W1f;
    const bool full = (t0 + 32) <= len;  // wave-uniform
    const int tb = t0 + th * 16;

    f4 acc[2][8] = {};

    const float* xptr = x + ((size_t)b * C_ + c_base + kc) * T_ + tb;
    float4 xv0 = ((const float4*)xptr)[0];
    float4 xv1 = ((const float4*)xptr)[1];
    float4 xv2 = ((const float4*)xptr)[2];
    float4 xv3 = ((const float4*)xptr)[3];

    for (int step = 0; step < 24; ++step) {
        float xs[16];
        *(float4*)&xs[0]  = xv0; *(float4*)&xs[4]  = xv1;
        *(float4*)&xs[8]  = xv2; *(float4*)&xs[12] = xv3;
        if (step < 23) {                 // prefetch next c-step
            xptr += 32 * (size_t)T_;
            xv0 = ((const float4*)xptr)[0];
            xv1 = ((const float4*)xptr)[1];
            xv2 = ((const float4*)xptr)[2];
            xv3 = ((const float4*)xptr)[3];
        }
        const float2 cr =
            carryT[((size_t)b * M32_ + m) * C_ + c_base + step * 32 + kc];

        // lane totals over its 16 t
        float ls1 = 0.f, ls2 = 0.f;
        if (full) {
#pragma unroll
            for (int j = 0; j < 16; ++j) { ls1 += xs[j]; ls2 += xs[j] * xs[j]; }
        } else {
#pragma unroll
            for (int j = 0; j < 16; ++j) {
                float mv = (tb + j < len) ? xs[j] : 0.f;
                ls1 += mv; ls2 += mv * xs[j];
            }
        }
        const float o1 = __shfl_xor(ls1, 1, 64);
        const float o2 = __shfl_xor(ls2, 1, 64);
        float r1 = cr.x + (th ? o1 : 0.f);
        float r2 = cr.y + (th ? o2 : 0.f);
#pragma unroll
        for (int j = 0; j < 16; ++j) {
            const float xval = xs[j];
            const float mv = (full || (tb + j < len)) ? xval : 0.f;
            r1 += mv; r2 += mv * xval;
            const float rn = __builtin_amdgcn_rcpf((float)min(tb + j + 1, len));
            const float mn = r1 * rn;
            const float var = r2 * rn - mn * mn;
            const float sd = sqrtf(fmaxf(var, 1e-12f));
            const int row = th * 16 + j;
            sc[row * SCW_ + kc]      = (_Float16)xval;
            sc[row * SCW_ + 32 + kc] = (_Float16)mn;
            sc[row * SCW_ + 64 + kc] = (_Float16)sd;
        }
        // within-wave LDS ordering via lgkmcnt; no barrier needed
        const int t15 = lane & 15, k8 = lane >> 4;
        const int kbS = s * 24 + step;
#pragma unroll
        for (int p = 0; p < 3; ++p) {
            h8 bf0 = *(const h8*)&sc[t15 * SCW_ + p * 32 + k8 * 8];
            h8 bf1 = *(const h8*)&sc[(16 + t15) * SCW_ + p * 32 + k8 * 8];
            const int kb = p * 48 + kbS;
#pragma unroll
            for (int ii = 0; ii < 8; ++ii) {
                h8 af = W1f8[(size_t)(kb * 8 + ii) * 64 + lane];
                acc[0][ii] = __builtin_amdgcn_mfma_f32_16x16x32_f16(af, bf0, acc[0][ii], 0, 0, 0);
                acc[1][ii] = __builtin_amdgcn_mfma_f32_16x16x32_f16(af, bf1, acc[1][ii], 0, 0, 0);
            }
        }
    }

    // split-K reduce + epilogue (the only 2 barriers)
    __syncthreads();
    float* red_f = (float*)smem;
    if (s == 1) {
        float* r = red_f + tch * 4096;
#pragma unroll
        for (int nn = 0; nn < 2; ++nn)
#pragma unroll
            for (int ii = 0; ii < 8; ++ii)
#pragma unroll
                for (int rg = 0; rg < 4; ++rg)
                    r[(nn * 32 + ii * 4 + rg) * 64 + lane] = acc[nn][ii][rg];
    }
    __syncthreads();
    if (s == 0) {
        float* r = red_f + tch * 4096;
        const int q = lane >> 4;
#pragma unroll
        for (int nn = 0; nn < 2; ++nn) {
            float pr = 0.f;
#pragma unroll
            for (int ii = 0; ii < 8; ++ii)
#pragma unroll
                for (int rg = 0; rg < 4; ++rg) {
                    float v = acc[nn][ii][rg] + r[(nn * 32 + ii * 4 + rg) * 64 + lane];
                    int a = ii * 16 + q * 4 + rg;
                    pr += tanhf(v + s_b1[a]) * s_w2[a];
                }
            pr += __shfl_xor(pr, 16, 64);
            pr += __shfl_xor(pr, 32, 64);
            if (lane < 16)
                logits[(size_t)b * T_ + t0 + nn * 16 + lane] = pr;
        }
    }
}

// ---------------- kernel 3: softmax prep (e, cumsum Z) per b ----------------
// b2 and the max-subtraction cancel in the e/Z ratios used downstream.
__global__ __launch_bounds__(1024) void k3_softmax(
    const float* __restrict__ logits, float* __restrict__ earr,
    float* __restrict__ zarr)
{
    __shared__ float wsum[16];
    const int b = blockIdx.x, tid = threadIdx.x, lane = tid & 63, w = tid >> 6;
    float4 v = *(const float4*)(logits + (size_t)b * T_ + tid * 4);
    float e0 = expf(v.x), e1 = expf(v.y), e2 = expf(v.z), e3 = expf(v.w);
    float s = (e0 + e1) + (e2 + e3);
    float V = s;
#pragma unroll
    for (int d = 1; d < 64; d <<= 1) {
        float o = __shfl_up(V, d, 64);
        if (lane >= d) V += o;
    }
    if (lane == 63) wsum[w] = V;
    __syncthreads();
    float wb = 0.f;
#pragma unroll
    for (int i = 0; i < 16; ++i) wb += (i < w) ? wsum[i] : 0.f;
    float run = wb + (V - s);
    float4 ev, zv;
    ev.x = e0; run += e0; zv.x = run;
    ev.y = e1; run += e1; zv.y = run;
    ev.z = e2; run += e2; zv.z = run;
    ev.w = e3; run += e3; zv.w = run;
    *(float4*)(earr + (size_t)b * T_ + tid * 4) = ev;
    *(float4*)(zarr + (size_t)b * T_ + tid * 4) = zv;
}

// ---------------- kernel 4: weighted running mean/std + final reduce --------
__global__ __launch_bounds__(256) void k4_wstats(
    const float* __restrict__ x, const float* __restrict__ earr,
    const float* __restrict__ zarr, float* __restrict__ out)
{
    const int rowid = blockIdx.x * 4 + (threadIdx.x >> 6);
    const int lane  = threadIdx.x & 63;
    const int b = rowid / C_;
    const int c = rowid - b * C_;
    const float* xr = x + (size_t)rowid * T_;
    const float* er = earr + (size_t)b * T_;
    const float* zr = zarr + (size_t)b * T_;
    float am = 0.f, asd = 0.f;
    float baseS = 0.f, baseD = 0.f;
#pragma unroll
    for (int g = 0; g < 16; ++g) {
        const int off = g * 256 + lane * 4;
        float4 xv = *(const float4*)(xr + off);
        float4 ev = *(const float4*)(er + off);
        float4 zv = *(const float4*)(zr + off);
        float s0 = ev.x * xv.x;
        float s1 = s0 + ev.y * xv.y;
        float s2 = s1 + ev.z * xv.z;
        float s3 = s2 + ev.w * xv.w;
        float V = s3;
#pragma unroll
        for (int d = 1; d < 64; d <<= 1) {
            float o = __shfl_up(V, d, 64);
            if (lane >= d) V += o;
        }
        const float Sx = baseS + (V - s3);
        baseS += __shfl(V, 63, 64);
        const float rz0 = __builtin_amdgcn_rcpf(zv.x);
        const float rz1 = __builtin_amdgcn_rcpf(zv.y);
        const float rz2 = __builtin_amdgcn_rcpf(zv.z);
        const float rz3 = __builtin_amdgcn_rcpf(zv.w);
        const float wm0 = (Sx + s0) * rz0;
        const float wm1 = (Sx + s1) * rz1;
        const float wm2 = (Sx + s2) * rz2;
        const float wm3 = (Sx + s3) * rz3;
        am += (wm0 + wm1) + (wm2 + wm3);
        const float d0 = xv.x - wm0;
        const float d1 = xv.y - wm1;
        const float d2 = xv.z - wm2;
        const float d3 = xv.w - wm3;
        float q0 = ev.x * d0 * d0;
        float q1 = q0 + ev.y * d1 * d1;
        float q2 = q1 + ev.z * d2 * d2;
        float q3 = q2 + ev.w * d3 * d3;
        float W = q3;
#pragma unroll
        for (int d = 1; d < 64; d <<= 1) {
            float o = __shfl_up(W, d, 64);
            if (lane >= d) W += o;
        }
        const float Dx = baseD + (W - q3);
        baseD += __shfl(W, 63, 64);
        const float v0 = (Dx + q0) * rz0;
        const float v1 = (Dx + q1) * rz1;
        const float v2 = (Dx + q2) * rz2;
        const float v3 = (Dx + q3) * rz3;
        asd += (sqrtf(fmaxf(v0, 1e-12f)) + sqrtf(fmaxf(v1, 1e-12f)))
             + (sqrtf(fmaxf(v2, 1e-12f)) + sqrtf(fmaxf(v3, 1e-12f)));
    }
#pragma unroll
    for (int d = 1; d < 64; d <<= 1) {
        am  += __shfl_xor(am, d, 64);
        asd += __shfl_xor(asd, d, 64);
    }
    if (lane == 0) {
        out[(size_t)b * (2 * C_) + c]      = am  * (1.f / 4096.f);
        out[(size_t)b * (2 * C_) + C_ + c] = asd * (1.f / 4096.f);
    }
}

extern "C" void kernel_launch(void* const* d_in, const int* in_sizes, int n_in,
                              void* d_out, int out_size, void* d_ws, size_t ws_size,
                              hipStream_t stream) {
    const float* x    = (const float*)d_in[0];
    const int*   lens = (const int*)d_in[1];
    const float* W1   = (const float*)d_in[2];
    const float* b1   = (const float*)d_in[3];
    const float* W2   = (const float*)d_in[4];
    float* out = (float*)d_out;
    char* ws = (char*)d_ws;

    // ws layout (~26.8 MB):
    float2*    carry  = (float2*)ws;                     // 8*1536*128*8 = 12,582,912
    float2*    carryT = (float2*)(ws + 12582912);        //               12,582,912
    _Float16*  W1f    = (_Float16*)(ws + 25165824);      //                1,179,648
    float*     logits = (float*)(ws + 26345472);         //                  131,072
    float*     earr   = (float*)(ws + 26476544);         //                  131,072
    float*     zarr   = (float*)(ws + 26607616);         //                  131,072

    k0_pack   <<<(A_ * K3_ + 255) / 256, 256, 0, stream>>>(W1, W1f);
    k1_carry  <<<(B_ * C_) / 4, 256, 0, stream>>>(x, lens, carry);
    k1b_T     <<<B_ * 48, 256, 0, stream>>>(carry, carryT);
    k2f       <<<B_ * 64, 256, 0, stream>>>(x, lens, carryT, W1f, b1, W2, logits);
    k3_softmax<<<B_, 1024, 0, stream>>>(logits, earr, zarr);
    k4_wstats <<<(B_ * C_) / 4, 256, 0, stream>>>(x, earr, zarr, out);
}